// Round 3
// baseline (356.278 us; speedup 1.0000x reference)
//
#include <hip/hip_runtime.h>

// NeuralFM forward, MI355X (gfx950).
// B=16384, F=50, D=64, L1=128, L2=64.
// R3: barrier-free (all LDS is wave-private; one wave = one instruction
// stream, compiler inserts lgkmcnt waits), 2048 blocks (RPW=2) for finer
// load-balance, gather keeps 1KB/instruction via (row, field-parity)
// half-wave mapping + shfl_xor(32) combine.

#define NFIELDS 50
#define HIDDEN  64
#define L1N     128
#define L2N     64
#define RPW     2                  // rows per wave
#define WAVES   4                  // waves per block
#define ROWS_PER_BLOCK (RPW * WAVES)   // 8

__global__ __launch_bounds__(256, 4) void neuralfm_kernel(
    const int*   __restrict__ features,   // [B, 50]
    const float* __restrict__ emb,        // [1e6, 64]
    const float* __restrict__ bias_t,     // [1e6]
    const float* __restrict__ w_bias,     // [1]
    const float* __restrict__ W1,         // [64, 128]
    const float* __restrict__ b1,         // [128]
    const float* __restrict__ W2,         // [128, 64]
    const float* __restrict__ b2,         // [64]
    const float* __restrict__ Wp,         // [64]
    const float* __restrict__ bp,         // [1]
    float*       __restrict__ out)        // [B]
{
    // All LDS is wave-private: no __syncthreads anywhere.
    __shared__ int    sIdx[WAVES][RPW * NFIELDS];        // 1.6 KB
    __shared__ float4 sFm4[WAVES][RPW * HIDDEN / 4];     // 2 KB
    __shared__ float  sH1 [WAVES][RPW * L1N];            // 4 KB

    const int tid  = threadIdx.x;
    const int wave = tid >> 6;
    const int lane = tid & 63;
    const int le   = lane & 15;          // dim-quad within a row
    const int r    = (lane >> 4) & 1;    // row (0/1) this lane serves in gather
    const int fg   = lane >> 5;          // field-parity group (0/1)
    const int row0 = blockIdx.x * ROWS_PER_BLOCK + wave * RPW;

    // ---- phase 0: coalesced index load (100 contiguous ints per wave) ----
    const int idx_base = row0 * NFIELDS;
    #pragma unroll
    for (int t = lane; t < RPW * NFIELDS; t += 64)
        sIdx[wave][t] = features[idx_base + t];

    // ---- early first-order bias gather: stays in flight through the MLP ----
    float biasacc[RPW];
    #pragma unroll
    for (int r2 = 0; r2 < RPW; ++r2) biasacc[r2] = 0.f;
    if (lane < NFIELDS) {
        #pragma unroll
        for (int r2 = 0; r2 < RPW; ++r2)
            biasacc[r2] = bias_t[sIdx[wave][r2 * NFIELDS + lane]];
    }

    // ---- phase 1: embedding gather + FM pooling ----
    // lanes 0-15: row0/even fields; 16-31: row1/even; 32-47: row0/odd;
    // 48-63: row1/odd  -> each instruction moves 4 x 256B rows = 1 KB.
    const float4* __restrict__ emb4 = (const float4*)emb;
    const int* myIdx = &sIdx[wave][r * NFIELDS];
    float sx = 0.f, sy = 0.f, sz = 0.f, sw = 0.f;   // sum (my half of fields)
    float qx = 0.f, qy = 0.f, qz = 0.f, qw = 0.f;   // sum of squares
    #pragma unroll
    for (int i = 0; i < NFIELDS / 2; ++i) {
        const int    idx = myIdx[2 * i + fg];              // LDS broadcast
        const float4 v   = emb4[(size_t)idx * (HIDDEN / 4) + le];
        sx += v.x; sy += v.y; sz += v.z; sw += v.w;
        qx += v.x * v.x; qy += v.y * v.y; qz += v.z * v.z; qw += v.w * v.w;
    }
    // combine the two field-parity halves (lane ^ 32 holds the other half)
    sx += __shfl_xor(sx, 32, 64); sy += __shfl_xor(sy, 32, 64);
    sz += __shfl_xor(sz, 32, 64); sw += __shfl_xor(sw, 32, 64);
    qx += __shfl_xor(qx, 32, 64); qy += __shfl_xor(qy, 32, 64);
    qz += __shfl_xor(qz, 32, 64); qw += __shfl_xor(qw, 32, 64);

    if (fg == 0) {  // lanes 0-31 hold complete sums for rows 0/1
        float4 fm;
        fm.x = 0.5f * (sx * sx - qx);
        fm.y = 0.5f * (sy * sy - qy);
        fm.z = 0.5f * (sz * sz - qz);
        fm.w = 0.5f * (sw * sw - qw);
        sFm4[wave][r * (HIDDEN / 4) + le] = fm;
    }

    // ---- phase 2: h1 = relu(fm @ W1 + b1); lane owns outputs {lane, lane+64} ----
    float h1a[RPW], h1b[RPW];
    #pragma unroll
    for (int r2 = 0; r2 < RPW; ++r2) { h1a[r2] = 0.f; h1b[r2] = 0.f; }

    for (int dq = 0; dq < HIDDEN / 4; ++dq) {
        float w0[4], w1[4];
        #pragma unroll
        for (int c = 0; c < 4; ++c) {
            w0[c] = W1[(4 * dq + c) * L1N + lane];          // coalesced, L2-hot
            w1[c] = W1[(4 * dq + c) * L1N + 64 + lane];
        }
        #pragma unroll
        for (int r2 = 0; r2 < RPW; ++r2) {
            const float4 fv = sFm4[wave][r2 * (HIDDEN / 4) + dq];  // b128 broadcast
            h1a[r2] += fv.x * w0[0] + fv.y * w0[1] + fv.z * w0[2] + fv.w * w0[3];
            h1b[r2] += fv.x * w1[0] + fv.y * w1[1] + fv.z * w1[2] + fv.w * w1[3];
        }
    }
    const float bias1a = b1[lane];
    const float bias1b = b1[64 + lane];
    #pragma unroll
    for (int r2 = 0; r2 < RPW; ++r2) {
        sH1[wave][r2 * L1N + lane]      = fmaxf(h1a[r2] + bias1a, 0.f);
        sH1[wave][r2 * L1N + 64 + lane] = fmaxf(h1b[r2] + bias1b, 0.f);
    }

    // ---- phase 3: h2 = relu(h1 @ W2 + b2); lane owns output `lane` ----
    const float4* sH14 = (const float4*)&sH1[wave][0];
    float h2[RPW];
    #pragma unroll
    for (int r2 = 0; r2 < RPW; ++r2) h2[r2] = 0.f;

    for (int jq = 0; jq < L1N / 4; ++jq) {
        float w[4];
        #pragma unroll
        for (int c = 0; c < 4; ++c)
            w[c] = W2[(4 * jq + c) * L2N + lane];           // coalesced, L2-hot
        #pragma unroll
        for (int r2 = 0; r2 < RPW; ++r2) {
            const float4 hv = sH14[r2 * (L1N / 4) + jq];    // b128 broadcast
            h2[r2] += hv.x * w[0] + hv.y * w[1] + hv.z * w[2] + hv.w * w[3];
        }
    }
    const float bias2 = b2[lane];
    const float wp    = Wp[lane];

    float tot[RPW];
    #pragma unroll
    for (int r2 = 0; r2 < RPW; ++r2)
        tot[r2] = fmaxf(h2[r2] + bias2, 0.f) * wp + biasacc[r2];

    // ---- phase 4: wave reduce (pred + feature_bias), add global terms, store ----
    #pragma unroll
    for (int r2 = 0; r2 < RPW; ++r2) {
        float v = tot[r2];
        #pragma unroll
        for (int off = 32; off > 0; off >>= 1)
            v += __shfl_xor(v, off, 64);
        tot[r2] = v;
    }
    if (lane == 0) {
        const float c = bp[0] + w_bias[0];
        #pragma unroll
        for (int r2 = 0; r2 < RPW; ++r2)
            out[row0 + r2] = tot[r2] + c;
    }
}

extern "C" void kernel_launch(void* const* d_in, const int* in_sizes, int n_in,
                              void* d_out, int out_size, void* d_ws, size_t ws_size,
                              hipStream_t stream) {
    const int*   features = (const int*)  d_in[0];
    // d_in[1] = labels (values unused by the forward pass)
    const float* emb      = (const float*)d_in[2];
    const float* bias_t   = (const float*)d_in[3];
    const float* w_bias   = (const float*)d_in[4];
    const float* W1       = (const float*)d_in[5];
    const float* b1       = (const float*)d_in[6];
    const float* W2       = (const float*)d_in[7];
    const float* b2       = (const float*)d_in[8];
    const float* Wp       = (const float*)d_in[9];
    const float* bp       = (const float*)d_in[10];
    float*       out      = (float*)d_out;

    const int batch  = in_sizes[0] / NFIELDS;        // 16384
    const int blocks = batch / ROWS_PER_BLOCK;       // 2048

    neuralfm_kernel<<<blocks, 256, 0, stream>>>(
        features, emb, bias_t, w_bias, W1, b1, W2, b2, Wp, bp, out);
}